// Round 6
// baseline (688.730 us; speedup 1.0000x reference)
//
#include <hip/hip_runtime.h>

// ---------------------------------------------------------------------------
// Talking-heads attention. B=2, N=M=2048, D=1024, H=16, dh=64.
// R6: denom kernel (QK+exp -> lsum atomics), then attn_pv: 4-wave blocks own
// (16 i x 512 j x all 16 h); QK->exp/l->talk->LN->PV fused through small LDS;
// O accumulated with fp32 HW atomics. XCD-swizzled so K/V slices are
// L2-resident. Workspace = 54.75 MiB (proven safe).
// ---------------------------------------------------------------------------

typedef __attribute__((ext_vector_type(8))) short short8;
typedef __attribute__((ext_vector_type(4))) short short4v;
typedef __attribute__((ext_vector_type(4))) float float4v;
typedef unsigned short u16;
typedef unsigned int u32;

#define MFMA16(a, b, c) __builtin_amdgcn_mfma_f32_16x16x32_bf16((a), (b), (c), 0, 0, 0)

__device__ inline u16 f2bf(float f) {  // RNE f32->bf16 (inputs finite)
  unsigned u = __float_as_uint(f);
  u += 0x7FFFu + ((u >> 16) & 1u);
  return (u16)(u >> 16);
}

// ---------------------------- cast kernel ----------------------------------
__global__ __launch_bounds__(256) void cast_bf16(const float* __restrict__ in,
                                                 u16* __restrict__ out, int n) {
  int i = (blockIdx.x * 256 + threadIdx.x) * 8;
  if (i + 8 > n) return;
  float4v f0 = *(const float4v*)(in + i);
  float4v f1 = *(const float4v*)(in + i + 4);
  short8 o;
  o[0] = (short)f2bf(f0[0]); o[1] = (short)f2bf(f0[1]);
  o[2] = (short)f2bf(f0[2]); o[3] = (short)f2bf(f0[3]);
  o[4] = (short)f2bf(f1[0]); o[5] = (short)f2bf(f1[1]);
  o[6] = (short)f2bf(f1[2]); o[7] = (short)f2bf(f1[3]);
  *(short8*)(out + i) = o;
}

// ------------------------ projection GEMM ----------------------------------
template <int MODE>
__global__ __launch_bounds__(256, 4) void gemm_bt(const u16* __restrict__ A,
                                                  const u16* __restrict__ W,
                                                  u16* __restrict__ out0,
                                                  u16* __restrict__ out1) {
  __shared__ u16 As[64][40];
  __shared__ u16 Ws[64][40];
  const int t = threadIdx.x;
  const int wave = t >> 6, l = t & 63, l15 = l & 15, lq = l >> 4;
  const int r0 = blockIdx.x * 64, c0 = blockIdx.y * 64;
  const int srow = t >> 2, sch = t & 3;
  const u16* ag = A + (r0 + srow) * 1024 + sch * 8;
  const u16* wg = W + (c0 + srow) * 1024 + sch * 8;

  float4v acc[4];
#pragma unroll
  for (int i = 0; i < 4; ++i) acc[i] = (float4v){0.f, 0.f, 0.f, 0.f};

  short8 av = *(const short8*)ag;
  short8 wv = *(const short8*)wg;
  for (int kt = 0; kt < 32; ++kt) {
    __syncthreads();
    *(short8*)&As[srow][sch * 8] = av;
    *(short8*)&Ws[srow][sch * 8] = wv;
    __syncthreads();
    if (kt < 31) {
      av = *(const short8*)(ag + (kt + 1) * 32);
      wv = *(const short8*)(wg + (kt + 1) * 32);
    }
    short8 af = *(const short8*)&As[wave * 16 + l15][lq * 8];
#pragma unroll
    for (int fn = 0; fn < 4; ++fn) {
      short8 bf = *(const short8*)&Ws[fn * 16 + l15][lq * 8];
      acc[fn] = MFMA16(af, bf, acc[fn]);
    }
  }
#pragma unroll
  for (int fn = 0; fn < 4; ++fn) {
#pragma unroll
    for (int r = 0; r < 4; ++r) {
      int row = r0 + wave * 16 + lq * 4 + r;
      int col = c0 + fn * 16 + l15;
      int b = row >> 11, n = row & 2047;
      float v = acc[fn][r];
      if (MODE == 0) {
        v *= 0.125f;
        int h = col >> 6, d = col & 63;
        out0[(((b * 16 + h) * 2048 + n) << 6) + d] = f2bf(v);
      } else {
        if (col < 1024) {
          int h = col >> 6, d = col & 63;
          out0[(((b * 16 + h) * 2048 + n) << 6) + d] = f2bf(v);
        } else {
          int cc = col - 1024;
          int h = cc >> 6, d = cc & 63;
          out1[(((b * 16 + h) * 2048 + n) << 6) + d] = f2bf(v);
        }
      }
    }
  }
}

// --------------------------- V transpose -----------------------------------
__global__ __launch_bounds__(256) void transpose_v(const u16* __restrict__ vh,
                                                   u16* __restrict__ vt) {
  __shared__ u16 tile[64][72];
  const int t = threadIdx.x;
  const int j0 = blockIdx.x * 64, h = blockIdx.y, b = blockIdx.z;
  const u16* src = vh + (((b * 16 + h) * 2048 + j0) << 6);
  int row = t >> 2, c = t & 3;
  short8 v0 = *(const short8*)(src + row * 64 + c * 8);
  short8 v1 = *(const short8*)(src + row * 64 + (c + 4) * 8);
  *(short8*)&tile[row][c * 8] = v0;
  *(short8*)&tile[row][(c + 4) * 8] = v1;
  __syncthreads();
  int d = t >> 2, jc = t & 3;
  short8 o0, o1;
#pragma unroll
  for (int jj = 0; jj < 8; ++jj) o0[jj] = (short)tile[jc * 16 + jj][d];
#pragma unroll
  for (int jj = 0; jj < 8; ++jj) o1[jj] = (short)tile[jc * 16 + 8 + jj][d];
  u16* dst = vt + ((b * 16 + h) * 64 + d) * 2048 + j0 + jc * 16;
  *(short8*)dst = o0;
  *(short8*)(dst + 8) = o1;
}

// --------------------- softmax denominator kernel --------------------------
// grid 4096 linear: bh = bid&31 (-> XCD = bh%8: K slice L2-resident),
// it = (bid>>5)&31, jc = bid>>10. Block 256 = 4 waves; wave owns 16 i-rows,
// streams 512 j; partial sums -> fp32 atomics into lsum[(b*2048+i)*16+h].
__global__ __launch_bounds__(256) void denom_kernel(const u16* __restrict__ qh,
                                                    const u16* __restrict__ kh,
                                                    float* __restrict__ lsum) {
  const int bid = blockIdx.x;
  const int bh = bid & 31, it = (bid >> 5) & 31, jc = bid >> 10;
  const int wv = threadIdx.x >> 6;
  const int i0 = it * 64 + wv * 16;
  const int l = threadIdx.x & 63, l15 = l & 15, lq = l >> 4;
  const u16* qbase = qh + ((bh * 2048 + i0) << 6);
  short8 qf0 = *(const short8*)(qbase + l15 * 64 + lq * 8);
  short8 qf1 = *(const short8*)(qbase + l15 * 64 + 32 + lq * 8);
  const u16* kbase = kh + ((bh * 2048 + jc * 512) << 6);

  float ps0 = 0.f, ps1 = 0.f, ps2 = 0.f, ps3 = 0.f;
  short8 k00 = *(const short8*)(kbase + l15 * 64 + lq * 8);
  short8 k01 = *(const short8*)(kbase + l15 * 64 + 32 + lq * 8);
  short8 k10 = *(const short8*)(kbase + (16 + l15) * 64 + lq * 8);
  short8 k11 = *(const short8*)(kbase + (16 + l15) * 64 + 32 + lq * 8);
  for (int jt = 0; jt < 16; ++jt) {
    short8 n00, n01, n10, n11;
    if (jt < 15) {
      const u16* kp = kbase + (((jt + 1) * 32) << 6);
      n00 = *(const short8*)(kp + l15 * 64 + lq * 8);
      n01 = *(const short8*)(kp + l15 * 64 + 32 + lq * 8);
      n10 = *(const short8*)(kp + (16 + l15) * 64 + lq * 8);
      n11 = *(const short8*)(kp + (16 + l15) * 64 + 32 + lq * 8);
    }
    float4v s0 = {0.f, 0.f, 0.f, 0.f}, s1 = {0.f, 0.f, 0.f, 0.f};
    s0 = MFMA16(qf0, k00, s0);
    s0 = MFMA16(qf1, k01, s0);
    s1 = MFMA16(qf0, k10, s1);
    s1 = MFMA16(qf1, k11, s1);
    ps0 += __expf(s0[0]) + __expf(s1[0]);
    ps1 += __expf(s0[1]) + __expf(s1[1]);
    ps2 += __expf(s0[2]) + __expf(s1[2]);
    ps3 += __expf(s0[3]) + __expf(s1[3]);
    k00 = n00; k01 = n01; k10 = n10; k11 = n11;
  }
#pragma unroll
  for (int d = 1; d < 16; d <<= 1) {
    ps0 += __shfl_xor(ps0, d);
    ps1 += __shfl_xor(ps1, d);
    ps2 += __shfl_xor(ps2, d);
    ps3 += __shfl_xor(ps3, d);
  }
  if (l15 == 0) {
    const int b = bh >> 4, h = bh & 15;
    float* o = lsum + ((b * 2048) + i0 + lq * 4) * 16 + h;
    unsafeAtomicAdd(o, ps0);
    unsafeAtomicAdd(o + 16, ps1);
    unsafeAtomicAdd(o + 32, ps2);
    unsafeAtomicAdd(o + 48, ps3);
  }
}

// ----------------- fused attn: QK->exp/l->talk->LN->PV ---------------------
// grid 1024 linear: slot = bid&7 -> (jc = slot>>1, b = slot&1) pinned per XCD
// (K+V slice ~2MB L2-resident); it = bid>>3. Block 256 = 4 waves.
// Block owns 16 i-rows x 512 j x all 16 heads. 16 subtiles of 32 j:
//   wave computes QK for 4 heads -> exp * (1/l) -> P_lds[e=i*32+jl][h(36)]
//   barrier -> talk MFMA (Wtalk A-frag, K=32 zero-padded) + per-cell LN ->
//   Y_lds[g][i][j(36)] -> barrier -> PV MFMA for 4 g/wave, regs.
// Epilogue: fp32 HW atomics into zeroed out (4 j-chunks per O element).
__global__ __launch_bounds__(256) void attn_pv(
    const u16* __restrict__ qh, const u16* __restrict__ kh,
    const u16* __restrict__ vt, const float* __restrict__ lsum,
    const float* __restrict__ wtalk, const float* __restrict__ gamma,
    const float* __restrict__ beta, float* __restrict__ out) {
  __shared__ u16 P_lds[512 * 36];      // [e][36]; h-slots 16..35 stay 0
  __shared__ u16 Y_lds[16 * 16 * 36];  // [g][i][36]

  const int tid = threadIdx.x;
  const int wv = tid >> 6, l = tid & 63, l15 = l & 15, lq = l >> 4;
  const int slot = blockIdx.x & 7;
  const int jc = slot >> 1, b = slot & 1;
  const int it = blockIdx.x >> 3;
  const int i0 = it * 16, jbase = jc * 512;
  const int hbase = wv * 4;

  for (int z = tid; z < 512 * 36; z += 256) P_lds[z] = 0;

  // Wtalk A-fragment: A[g=l15][h=lq*8+t], zero for h>=16
  short8 wfrag;
#pragma unroll
  for (int t8 = 0; t8 < 8; ++t8) {
    int h = lq * 8 + t8;
    wfrag[t8] = (h < 16) ? (short)f2bf(wtalk[l15 * 16 + h]) : (short)0;
  }
  float gam[4], bet[4];
#pragma unroll
  for (int r = 0; r < 4; ++r) {
    gam[r] = gamma[lq * 4 + r];
    bet[r] = beta[lq * 4 + r];
  }
  // 1/l for this wave's 4 heads x 4 i-rows (i = i0 + lq*4 + r)
  float rl[4][4];
#pragma unroll
  for (int hh = 0; hh < 4; ++hh)
#pragma unroll
    for (int r = 0; r < 4; ++r)
      rl[hh][r] =
          1.0f / lsum[((b * 2048) + i0 + lq * 4 + r) * 16 + hbase + hh];
  // Q fragments for 4 heads
  short8 qf[4][2];
#pragma unroll
  for (int hh = 0; hh < 4; ++hh) {
    const u16* qp =
        qh + (((b * 16 + hbase + hh) * 2048 + i0 + l15) << 6) + lq * 8;
    qf[hh][0] = *(const short8*)qp;
    qf[hh][1] = *(const short8*)(qp + 32);
  }

  float4v acc[4][4];
#pragma unroll
  for (int gg = 0; gg < 4; ++gg)
#pragma unroll
    for (int dd = 0; dd < 4; ++dd) acc[gg][dd] = (float4v){0.f, 0.f, 0.f, 0.f};

  __syncthreads();  // P pad zero-init visible

  for (int sj = 0; sj < 16; ++sj) {
    const int j0 = jbase + sj * 32;
    // --- QK + exp/l -> P_lds, 4 heads per wave ---
#pragma unroll
    for (int hh = 0; hh < 4; ++hh) {
      const int h = hbase + hh;
      const u16* kp = kh + (((b * 16 + h) * 2048 + j0) << 6);
      short8 k00 = *(const short8*)(kp + l15 * 64 + lq * 8);
      short8 k01 = *(const short8*)(kp + l15 * 64 + 32 + lq * 8);
      short8 k10 = *(const short8*)(kp + (16 + l15) * 64 + lq * 8);
      short8 k11 = *(const short8*)(kp + (16 + l15) * 64 + 32 + lq * 8);
      float4v s0 = {0.f, 0.f, 0.f, 0.f}, s1 = {0.f, 0.f, 0.f, 0.f};
      s0 = MFMA16(qf[hh][0], k00, s0);
      s0 = MFMA16(qf[hh][1], k01, s0);
      s1 = MFMA16(qf[hh][0], k10, s1);
      s1 = MFMA16(qf[hh][1], k11, s1);
#pragma unroll
      for (int r = 0; r < 4; ++r) {
        const int e0 = (lq * 4 + r) * 32 + l15;
        P_lds[e0 * 36 + h] = f2bf(__expf(s0[r]) * rl[hh][r]);
        P_lds[(e0 + 16) * 36 + h] = f2bf(__expf(s1[r]) * rl[hh][r]);
      }
    }
    __syncthreads();
    // --- talk MFMA + LN -> Y_lds; wave covers e in [wv*128, wv*128+128) ---
#pragma unroll
    for (int c = 0; c < 8; ++c) {
      const int e = wv * 128 + c * 16 + l15;
      const u16* pp = &P_lds[e * 36 + lq * 8];
      short4v x0 = *(const short4v*)pp;
      short4v x1 = *(const short4v*)(pp + 4);
      short8 pb = __builtin_shufflevector(x0, x1, 0, 1, 2, 3, 4, 5, 6, 7);
      float4v t = MFMA16(wfrag, pb, ((float4v){0.f, 0.f, 0.f, 0.f}));
      float sum = t[0] + t[1] + t[2] + t[3];
      sum += __shfl_xor(sum, 16);
      sum += __shfl_xor(sum, 32);
      float mu = sum * 0.0625f;
      float ss = t[0] * t[0] + t[1] * t[1] + t[2] * t[2] + t[3] * t[3];
      ss += __shfl_xor(ss, 16);
      ss += __shfl_xor(ss, 32);
      float var = ss * 0.0625f - mu * mu;
      float rs = rsqrtf(var + 1e-5f);
      const int ii = e >> 5, jl = e & 31;
#pragma unroll
      for (int r = 0; r < 4; ++r) {
        float y = (t[r] - mu) * rs * gam[r] + bet[r];
        Y_lds[((lq * 4 + r) * 16 + ii) * 36 + jl] = f2bf(y);
      }
    }
    __syncthreads();
    // --- PV for 4 g per wave ---
#pragma unroll
    for (int gg = 0; gg < 4; ++gg) {
      const int g = hbase + gg;
      short8 yf = *(const short8*)&Y_lds[(g * 16 + l15) * 36 + lq * 8];
      const u16* vb = vt + ((size_t)(b * 16 + g) * 64) * 2048 + j0 + lq * 8;
#pragma unroll
      for (int dd = 0; dd < 4; ++dd) {
        short8 vf = *(const short8*)(vb + (dd * 16 + l15) * 2048);
        acc[gg][dd] = MFMA16(yf, vf, acc[gg][dd]);
      }
    }
  }
  // epilogue: accumulate partial O (4 jc-chunks per element)
#pragma unroll
  for (int gg = 0; gg < 4; ++gg)
#pragma unroll
    for (int dd = 0; dd < 4; ++dd)
#pragma unroll
      for (int r = 0; r < 4; ++r)
        unsafeAtomicAdd(out + (size_t)((b * 2048) + i0 + lq * 4 + r) * 1024 +
                            (hbase + gg) * 64 + dd * 16 + l15,
                        acc[gg][dd][r]);
}

// ----------------------------- launcher ------------------------------------
extern "C" void kernel_launch(void* const* d_in, const int* in_sizes, int n_in,
                              void* d_out, int out_size, void* d_ws,
                              size_t ws_size, hipStream_t stream) {
  const float* x = (const float*)d_in[0];
  const float* ctx = (const float*)d_in[1];
  const float* Wq = (const float*)d_in[2];
  const float* Wkv = (const float*)d_in[3];
  const float* Wtalk = (const float*)d_in[4];
  const float* gam = (const float*)d_in[5];
  const float* bet = (const float*)d_in[6];
  float* out = (float*)d_out;

  u16* xb = (u16*)d_ws;            // 4  Mi elems
  u16* cb = xb + 4194304;          // 4  Mi
  u16* wqb = cb + 4194304;         // 1  Mi
  u16* wkvb = wqb + 1048576;       // 2  Mi
  u16* qhb = wkvb + 2097152;       // 4  Mi  [b][h][n][64]
  u16* khb = qhb + 4194304;        // 4  Mi  [b][h][j][64]
  u16* vhb = khb + 4194304;        // 4  Mi  [b][h][j][64]
  u16* vtb = vhb + 4194304;        // 4  Mi  [b][h][d][2048]
  float* lsum = (float*)(vtb + 4194304);  // 65536 fp32 (256 KB)
  // total ~54.75 MiB (proven-safe budget)

  hipMemsetAsync(lsum, 0, 262144, stream);
  hipMemsetAsync(out, 0, (size_t)2 * 2048 * 1024 * sizeof(float), stream);

  cast_bf16<<<2048, 256, 0, stream>>>(x, xb, 4194304);
  cast_bf16<<<2048, 256, 0, stream>>>(ctx, cb, 4194304);
  cast_bf16<<<512, 256, 0, stream>>>(Wq, wqb, 1048576);
  cast_bf16<<<1024, 256, 0, stream>>>(Wkv, wkvb, 2097152);

  gemm_bt<0><<<dim3(64, 16), 256, 0, stream>>>(xb, wqb, qhb, nullptr);
  gemm_bt<1><<<dim3(64, 32), 256, 0, stream>>>(cb, wkvb, khb, vhb);

  transpose_v<<<dim3(32, 16, 2), 256, 0, stream>>>(vhb, vtb);

  denom_kernel<<<4096, 256, 0, stream>>>(qhb, khb, lsum);

  attn_pv<<<1024, 256, 0, stream>>>(qhb, khb, vtb, lsum, Wtalk, gam, bet, out);
}